// Round 17
// baseline (82.993 us; speedup 1.0000x reference)
//
#include <hip/hip_runtime.h>
#include <math.h>

#define HW 16384
#define Wd 128

typedef __attribute__((ext_vector_type(8))) short short8;
typedef __attribute__((ext_vector_type(4))) float f32x4;

__device__ __forceinline__ unsigned cvt_pk_bf16(float a, float b) {
  unsigned r;                                   // r = bf16(a) | bf16(b)<<16
  asm("v_cvt_pk_bf16_f32 %0, %1, %2" : "=v"(r) : "v"(a), "v"(b));
  return r;
}

__device__ __forceinline__ unsigned short bf16r(float f) {
  unsigned int u = __float_as_uint(f);
  unsigned int r = (u + 0x7FFFu + ((u >> 16) & 1u)) >> 16;   // RNE
  return (unsigned short)r;
}

// ================= LAUNCH 1: mean | pw1 | prep | gate (block ranges) =========
__global__ void k_combo1(
    const float* __restrict__ x,
    const float* __restrict__ w1a, const float* __restrict__ b1a,
    const float* __restrict__ w1c, const float* __restrict__ b1c,
    const float* __restrict__ w211, const float* __restrict__ b211,
    const float* __restrict__ kbw, const float* __restrict__ kbb,
    const float* __restrict__ wproj,
    const float* __restrict__ wc2a, const float* __restrict__ bc2a,
    float* __restrict__ xmean, float* __restrict__ ha, float* __restrict__ hc,
    float* __restrict__ att, unsigned short* __restrict__ kwA,
    unsigned short* __restrict__ wp, float* __restrict__ m) {
  int blk = blockIdx.x;
  int tid = threadIdx.x;
  if (blk < 96) {
    // ---- mean ----
    int bc = blk;
    const float* p = x + (size_t)bc * HW;
    float s = 0.f;
    for (int i = tid; i < HW; i += 256) s += p[i];
    #pragma unroll
    for (int off = 32; off > 0; off >>= 1) s += __shfl_down(s, off, 64);
    __shared__ float wsum[4];
    int lane = tid & 63, wv = tid >> 6;
    if (lane == 0) wsum[wv] = s;
    __syncthreads();
    if (tid == 0)
      xmean[bc] = (wsum[0] + wsum[1] + wsum[2] + wsum[3]) * (1.f / 16384.f);
  } else if (blk < 2144) {
    // ---- pw1 (flattened (512,4)) ----
    int bid2 = blk - 96;
    int bx = bid2 & 511, quad = bid2 >> 9;
    int lane = tid & 63;
    int wv = __builtin_amdgcn_readfirstlane((int)(tid >> 6));
    int slot = __builtin_amdgcn_readfirstlane(quad * 4 + wv);
    int p = bx * 64 + lane;
    int b = p >> 14, sp = p & (HW - 1);
    const float* xb = x + (size_t)b * 48 * HW + sp;
    float xv[48];
    #pragma unroll
    for (int ci = 0; ci < 48; ci++) xv[ci] = xb[(size_t)ci * HW];
    float* hab = ha + (size_t)b * 96 * HW + sp;
    float* hcb = hc + (size_t)b * 96 * HW + sp;
    int c0 = slot * 6;
    for (int co = c0; co < c0 + 6; co++) {
      float aa = b1a[co], ac = b1c[co];
      const float* wa = w1a + co * 48;
      const float* wc = w1c + co * 48;
      #pragma unroll
      for (int ci = 0; ci < 48; ci++) { aa += wa[ci] * xv[ci]; ac += wc[ci] * xv[ci]; }
      hab[(size_t)co * HW] = aa;
      hcb[(size_t)co * HW] = ac;
    }
    float* ab = att + (size_t)b * 32 * HW + sp;
    int n0 = slot * 2;
    for (int n = n0; n < n0 + 2; n++) {
      float a2 = b211[n];
      const float* w2 = w211 + n * 48;
      #pragma unroll
      for (int ci = 0; ci < 48; ci++) a2 += w2[ci] * xv[ci];
      ab[(size_t)n * HW] = a2;
    }
  } else if (blk < 2546) {
    // ---- prep ----
    int blk2 = blk - 2144;
    if (blk2 < 384) {
      int e = blk2 * 256 + tid;                    // < 98304
      int k = e & 31, nc = (e >> 5) & 63, g = e >> 11;
      int n = nc >> 1, i = nc & 1;
      int q = k >> 3, j2 = k & 7;
      float v = 0.f;
      int jj = -1;
      if (q == 0)      { if (j2 < 5) jj = j2; }
      else if (q == 1) { if (j2 < 5) jj = 9 + j2; }
      else if (q == 2) { if (j2 < 4) jj = 5 + j2; }
      else             { if (j2 < 4) jj = 14 + j2; else if (j2 == 4) v = kbb[n * 96 + 2 * g + i]; }
      if (jj >= 0) v = kbw[n * 1728 + g * 36 + i * 18 + jj];
      kwA[e] = bf16r(v);
    } else {
      int e = (blk2 - 384) * 256 + tid;            // < 4608
      if (e < 4608) {
        float w = wproj[e];
        unsigned short h = bf16r(w);
        wp[e] = h;
        float hif = __uint_as_float((unsigned)h << 16);
        wp[4608 + e] = bf16r(w - hif);
      }
    }
  } else {
    // ---- gate ----
    int idx = (blk - 2546) * 256 + tid;            // < B*12*HW = 393216
    int sp = idx & (HW - 1);
    int bi = idx >> 14;                            // b*12+i
    int i = bi % 12, b = bi / 12;
    int r = sp >> 7, c = sp & 127;
    const float* xb = x + (size_t)b * 48 * HW;
    float t[2];
    #pragma unroll
    for (int half = 0; half < 2; half++) {
      int o = i + half * 12;
      float acc = bc2a[o];
      #pragma unroll
      for (int ic = 0; ic < 2; ic++) {
        const float* xc = xb + (size_t)(2 * o + ic) * HW;
        const float* wo = wc2a + o * 18 + ic * 9;
        #pragma unroll
        for (int t9 = 0; t9 < 9; t9++) {
          int rr = r + t9 / 3 - 1, cc = c + t9 % 3 - 1;
          float v = (((unsigned)rr < 128u) && ((unsigned)cc < 128u)) ? xc[rr * Wd + cc] : 0.f;
          acc += wo[t9] * v;
        }
      }
      t[half] = acc;
    }
    m[idx] = t[0] * t[1];
  }
}

// ================= LAUNCH 2: dw (inline sca) | att2 (block ranges) ===========
__global__ void k_combo2(
    const float* __restrict__ ha, const float* __restrict__ hc,
    const float* __restrict__ wdwa, const float* __restrict__ bdwa,
    const float* __restrict__ wdwc, const float* __restrict__ bdwc,
    const float* __restrict__ wsca, const float* __restrict__ bsca,
    const float* __restrict__ xmean,
    const float* __restrict__ m,
    const float* __restrict__ wc2b, const float* __restrict__ bc2b,
    const float* __restrict__ attg,
    float* __restrict__ x1g, float* __restrict__ uf, float* __restrict__ att) {
  int blk = blockIdx.x;
  int tid = threadIdx.x;
  if (blk < 3072) {
    // ---- dw, 4-px column strips; sca computed per block from xmean ----
    int idx = blk * 256 + tid;                     // < B*96*HW/4 = 786432
    int sp4 = idx & 4095;
    int bc = idx >> 12;                            // block-uniform
    int ch = bc % 96, bq = bc / 96;
    __shared__ float scs;
    if (tid == 0) {
      float a = bsca[ch];
      for (int ci = 0; ci < 48; ci++) a += wsca[ch * 48 + ci] * xmean[bq * 48 + ci];
      scs = a;
    }
    __syncthreads();
    int sp = sp4 * 4;
    int r = sp >> 7, c = sp & 127;                 // c in {0,4,...,124}
    const float* pa = ha + (size_t)bc * HW;
    const float* pc = hc + (size_t)bc * HW;
    bool cm = (c > 0), cp = (c < 124);
    float aa0 = bdwa[ch], aa1 = aa0, aa2 = aa0, aa3 = aa0;
    float gc0 = bdwc[ch], gc1 = gc0, gc2 = gc0, gc3 = gc0;
    #pragma unroll
    for (int ri = 0; ri < 3; ri++) {
      int rr = r + ri - 1;
      bool okr = ((unsigned)rr < 128u);
      const float* ra = pa + rr * Wd + c;
      const float* rc = pc + rr * Wd + c;
      float4 fa = okr ? *(const float4*)ra : make_float4(0.f, 0.f, 0.f, 0.f);
      float4 fc = okr ? *(const float4*)rc : make_float4(0.f, 0.f, 0.f, 0.f);
      float la = (okr && cm) ? ra[-1] : 0.f;
      float lc = (okr && cm) ? rc[-1] : 0.f;
      float ua = (okr && cp) ? ra[4] : 0.f;
      float uc = (okr && cp) ? rc[4] : 0.f;
      float wa0 = wdwa[ch * 9 + ri * 3], wa1 = wdwa[ch * 9 + ri * 3 + 1], wa2 = wdwa[ch * 9 + ri * 3 + 2];
      float wc0 = wdwc[ch * 9 + ri * 3], wc1 = wdwc[ch * 9 + ri * 3 + 1], wc2 = wdwc[ch * 9 + ri * 3 + 2];
      aa0 += wa0 * la   + wa1 * fa.x + wa2 * fa.y;
      aa1 += wa0 * fa.x + wa1 * fa.y + wa2 * fa.z;
      aa2 += wa0 * fa.y + wa1 * fa.z + wa2 * fa.w;
      aa3 += wa0 * fa.z + wa1 * fa.w + wa2 * ua;
      gc0 += wc0 * lc   + wc1 * fc.x + wc2 * fc.y;
      gc1 += wc0 * fc.x + wc1 * fc.y + wc2 * fc.z;
      gc2 += wc0 * fc.y + wc1 * fc.z + wc2 * fc.w;
      gc3 += wc0 * fc.z + wc1 * fc.w + wc2 * uc;
    }
    float sc = scs;
    const float k = 0.70710678118654752440f;
    float4 xg;
    xg.x = aa0 * 0.5f * (1.f + erff(aa0 * k)) * sc;
    xg.y = aa1 * 0.5f * (1.f + erff(aa1 * k)) * sc;
    xg.z = aa2 * 0.5f * (1.f + erff(aa2 * k)) * sc;
    xg.w = aa3 * 0.5f * (1.f + erff(aa3 * k)) * sc;
    *(float4*)(x1g + (size_t)bc * HW + sp) = xg;
    *(float4*)(uf + (size_t)bc * HW + sp) = make_float4(gc0, gc1, gc2, gc3);
  } else {
    // ---- att2 (flattened (512,4)): att += 1x1(m)*gamma, in place ----
    int bid2 = blk - 3072;
    int bx = bid2 & 511, quad = bid2 >> 9;
    int lane = tid & 63;
    int wv = __builtin_amdgcn_readfirstlane((int)(tid >> 6));
    int slot = __builtin_amdgcn_readfirstlane(quad * 4 + wv);
    int p = bx * 64 + lane;
    int b = p >> 14, sp = p & (HW - 1);
    float mv[12];
    const float* mb = m + (size_t)b * 12 * HW + sp;
    #pragma unroll
    for (int i = 0; i < 12; i++) mv[i] = mb[(size_t)i * HW];
    float* ab = att + (size_t)b * 32 * HW + sp;
    int n0 = slot * 2;
    for (int n = n0; n < n0 + 2; n++) {
      float a1 = bc2b[n];
      #pragma unroll
      for (int i = 0; i < 12; i++) a1 += wc2b[n * 12 + i] * mv[i];
      float* ap = ab + (size_t)n * HW;
      *ap = a1 * attg[n] + *ap;
    }
  }
}

// ---------------- K6: fused kba via MFMA, DUAL-PIXEL waves ----------
// grid (256,12) x 256. Block covers one image row (128 px) of batch b and
// 4 groups. Each lane owns pixels cA = wv*16+lo and cB = cA+64, processed as
// two parallel chains sharing the LDS A-frags (ds_read / staging halved per px).
__global__ __launch_bounds__(256) void k_kba(
    const float* __restrict__ uf, const float* __restrict__ x1g,
    const float* __restrict__ att, const unsigned short* __restrict__ kwA,
    const float* __restrict__ ga1, unsigned int* __restrict__ y2) {
  __shared__ __align__(16) short kwS[4 * 2048];    // 16 KB
  int tid = threadIdx.x;
  int lane = tid & 63;
  int wv = tid >> 6;
  int lo = lane & 15, hi = lane >> 4;
  int bid = blockIdx.x;                            // 0..255
  int b = bid >> 7;
  int row = bid & 127;
  int cA = wv * 16 + lo;                           // 0..63
  int spA = row * Wd + cA;
  int spB = spA + 64;
  int g0 = blockIdx.y * 4;

  {
    const short8* src = (const short8*)(kwA + g0 * 2048);
    short8* dst = (short8*)kwS;
    #pragma unroll
    for (int i = 0; i < 4; i++) dst[tid + 256 * i] = src[tid + 256 * i];
  }

  const float* ufb  = uf  + (size_t)b * 96 * HW;
  const float* x1gb = x1g + (size_t)b * 96 * HW;
  const float* attb = att + (size_t)b * 32 * HW;
  unsigned int* y2b = y2 + (size_t)b * 48 * HW;

  float attvA[8], attvB[8];
  #pragma unroll
  for (int mt = 0; mt < 4; mt++)
    #pragma unroll
    for (int q = 0; q < 2; q++) {
      const float* an = attb + (size_t)(8 * mt + 2 * hi + q) * HW;
      attvA[mt * 2 + q] = an[spA];
      attvB[mt * 2 + q] = an[spB];
    }

  // tap descriptors (shared rr/base; per-pixel column predicates)
  const float* pjA[5];
  const float* pjB[5];
  bool okA[5], okB[5];
  float dv[5];
  #pragma unroll
  for (int j2 = 0; j2 < 5; j2++) {
    int jj = (hi == 0) ? j2 : (hi == 1) ? 9 + j2 : (hi == 2) ? 5 + j2 : 14 + j2;
    bool real = (hi < 2) || (j2 < 4);
    if (real) {
      int ch = jj / 9, tap = jj % 9;
      int rr = row + tap / 3 - 1;
      int ccA = cA + tap % 3 - 1;                  // -1..64
      bool okr = ((unsigned)rr < 128u);
      okA[j2] = okr && (ccA >= 0);
      okB[j2] = okr && (ccA + 64 < 128);
      dv[j2] = 0.f;
      const float* base = ufb + (size_t)(2 * g0 + ch) * HW;
      int off = rr * Wd + ccA;
      pjA[j2] = base + (okA[j2] ? off : 0);
      pjB[j2] = base + (okB[j2] ? off + 64 : 0);
    } else {
      okA[j2] = false; okB[j2] = false;
      dv[j2] = (hi == 3) ? 1.f : 0.f;              // bias slot (q3, j2==4)
      pjA[j2] = ufb; pjB[j2] = ufb;
    }
  }

  float vTA[4][5], vTB[4][5];
  #pragma unroll
  for (int gi = 0; gi < 4; gi++)
    #pragma unroll
    for (int j2 = 0; j2 < 5; j2++) {
      vTA[gi][j2] = okA[j2] ? pjA[j2][(size_t)(2 * gi) * HW] : dv[j2];
      vTB[gi][j2] = okB[j2] ? pjB[j2][(size_t)(2 * gi) * HW] : dv[j2];
    }
  float x1vA[8], x1vB[8];
  #pragma unroll
  for (int k = 0; k < 8; k++) {
    const float* xn = x1gb + (size_t)(2 * g0 + k) * HW;
    x1vA[k] = xn[spA];
    x1vB[k] = xn[spB];
  }

  __syncthreads();

  #pragma unroll
  for (int gp = 0; gp < 2; gp++) {
    int g = g0 + 2 * gp;
    float* vaA = vTA[2 * gp];
    float* voA = vTA[2 * gp + 1];
    float* vaB = vTB[2 * gp];
    float* voB = vTB[2 * gp + 1];
    const short* kgE = kwS + (2 * gp) * 2048;
    const short* kgO = kgE + 2048;
    short8 afrE[4], afrO[4];
    #pragma unroll
    for (int mt = 0; mt < 4; mt++) {
      afrE[mt] = *(const short8*)(kgE + (16 * mt + lo) * 32 + hi * 8);
      afrO[mt] = *(const short8*)(kgO + (16 * mt + lo) * 32 + hi * 8);
    }
    union { unsigned u[4]; short8 s; } bAe, bAo, bBe, bBo;
    bAe.u[0] = cvt_pk_bf16(vaA[0], vaA[1]);
    bAe.u[1] = cvt_pk_bf16(vaA[2], vaA[3]);
    bAe.u[2] = cvt_pk_bf16(vaA[4], 0.f);
    bAe.u[3] = 0u;
    bAo.u[0] = cvt_pk_bf16(voA[0], voA[1]);
    bAo.u[1] = cvt_pk_bf16(voA[2], voA[3]);
    bAo.u[2] = cvt_pk_bf16(voA[4], 0.f);
    bAo.u[3] = 0u;
    bBe.u[0] = cvt_pk_bf16(vaB[0], vaB[1]);
    bBe.u[1] = cvt_pk_bf16(vaB[2], vaB[3]);
    bBe.u[2] = cvt_pk_bf16(vaB[4], 0.f);
    bBe.u[3] = 0u;
    bBo.u[0] = cvt_pk_bf16(voB[0], voB[1]);
    bBo.u[1] = cvt_pk_bf16(voB[2], voB[3]);
    bBo.u[2] = cvt_pk_bf16(voB[4], 0.f);
    bBo.u[3] = 0u;
    f32x4 aAe[4], aAo[4], aBe[4], aBo[4];
    f32x4 zero = {0.f, 0.f, 0.f, 0.f};
    #pragma unroll
    for (int mt = 0; mt < 4; mt++) {
      aAe[mt] = __builtin_amdgcn_mfma_f32_16x16x32_bf16(afrE[mt], bAe.s, zero, 0, 0, 0);
      aBe[mt] = __builtin_amdgcn_mfma_f32_16x16x32_bf16(afrE[mt], bBe.s, zero, 0, 0, 0);
      aAo[mt] = __builtin_amdgcn_mfma_f32_16x16x32_bf16(afrO[mt], bAo.s, zero, 0, 0, 0);
      aBo[mt] = __builtin_amdgcn_mfma_f32_16x16x32_bf16(afrO[mt], bBo.s, zero, 0, 0, 0);
    }
    // reduce over n for each of the 4 acc sets
    float sAe0 = 0.f, sAe1 = 0.f, sAo0 = 0.f, sAo1 = 0.f;
    float sBe0 = 0.f, sBe1 = 0.f, sBo0 = 0.f, sBo1 = 0.f;
    #pragma unroll
    for (int mt = 0; mt < 4; mt++) {
      float a0A = attvA[mt * 2 + 0], a1A = attvA[mt * 2 + 1];
      float a0B = attvB[mt * 2 + 0], a1B = attvB[mt * 2 + 1];
      sAe0 += a0A * aAe[mt][0] + a1A * aAe[mt][2];
      sAe1 += a0A * aAe[mt][1] + a1A * aAe[mt][3];
      sAo0 += a0A * aAo[mt][0] + a1A * aAo[mt][2];
      sAo1 += a0A * aAo[mt][1] + a1A * aAo[mt][3];
      sBe0 += a0B * aBe[mt][0] + a1B * aBe[mt][2];
      sBe1 += a0B * aBe[mt][1] + a1B * aBe[mt][3];
      sBo0 += a0B * aBo[mt][0] + a1B * aBo[mt][2];
      sBo1 += a0B * aBo[mt][1] + a1B * aBo[mt][3];
    }
    sAe0 += __shfl_xor(sAe0, 16); sAe0 += __shfl_xor(sAe0, 32);
    sAe1 += __shfl_xor(sAe1, 16); sAe1 += __shfl_xor(sAe1, 32);
    sAo0 += __shfl_xor(sAo0, 16); sAo0 += __shfl_xor(sAo0, 32);
    sAo1 += __shfl_xor(sAo1, 16); sAo1 += __shfl_xor(sAo1, 32);
    sBe0 += __shfl_xor(sBe0, 16); sBe0 += __shfl_xor(sBe0, 32);
    sBe1 += __shfl_xor(sBe1, 16); sBe1 += __shfl_xor(sBe1, 32);
    sBo0 += __shfl_xor(sBo0, 16); sBo0 += __shfl_xor(sBo0, 32);
    sBo1 += __shfl_xor(sBo1, 16); sBo1 += __shfl_xor(sBo1, 32);
    float cenAe = __shfl_xor(vaA[4], 16);
    float cenAo = __shfl_xor(voA[4], 16);
    float cenBe = __shfl_xor(vaB[4], 16);
    float cenBo = __shfl_xor(voB[4], 16);
    if (hi == 0) {
      int c0 = 2 * g;
      float g0e = ga1[c0], g0o = ga1[c0 + 1], g1e = ga1[c0 + 2], g1o = ga1[c0 + 3];
      // pixel A
      float xa0 = sAe0 * g0e + vaA[4];
      float xa1 = sAe1 * g0o + cenAe;
      y2b[(size_t)g * HW + spA] = cvt_pk_bf16(x1vA[4 * gp] * xa0, x1vA[4 * gp + 1] * xa1);
      float xb0 = sAo0 * g1e + voA[4];
      float xb1 = sAo1 * g1o + cenAo;
      y2b[(size_t)(g + 1) * HW + spA] = cvt_pk_bf16(x1vA[4 * gp + 2] * xb0, x1vA[4 * gp + 3] * xb1);
      // pixel B
      float ya0 = sBe0 * g0e + vaB[4];
      float ya1 = sBe1 * g0o + cenBe;
      y2b[(size_t)g * HW + spB] = cvt_pk_bf16(x1vB[4 * gp] * ya0, x1vB[4 * gp + 1] * ya1);
      float yb0 = sBo0 * g1e + voB[4];
      float yb1 = sBo1 * g1o + cenBo;
      y2b[(size_t)(g + 1) * HW + spB] = cvt_pk_bf16(x1vB[4 * gp + 2] * yb0, x1vB[4 * gp + 3] * yb1);
    }
  }
}

// ---------------- K7: project_out 96->48 via MFMA (W = bf16 hi + bf16 lo) -------
__global__ void k_proj(const unsigned int* __restrict__ y2, const unsigned short* __restrict__ wp,
                       const float* __restrict__ bproj, float* __restrict__ out) {
  int tid = threadIdx.x;
  int lane = tid & 63;
  int wv = tid >> 6;
  int lo = lane & 15, hi = lane >> 4;
  int p0 = blockIdx.x * 64 + wv * 16;
  int b = p0 >> 14;
  int sp = (p0 & (HW - 1)) + lo;
  const unsigned int* yb = y2 + (size_t)b * 48 * HW + sp;
  union { unsigned u[4]; short8 s; } bf[3];
  #pragma unroll
  for (int ks = 0; ks < 3; ks++)
    #pragma unroll
    for (int q = 0; q < 4; q++)
      bf[ks].u[q] = yb[(size_t)(ks * 16 + hi * 4 + q) * HW];
  f32x4 acc[3];
  #pragma unroll
  for (int t = 0; t < 3; t++)
    #pragma unroll
    for (int r = 0; r < 4; r++)
      acc[t][r] = bproj[16 * t + 4 * hi + r];
  #pragma unroll
  for (int t = 0; t < 3; t++) {
    #pragma unroll
    for (int ks = 0; ks < 3; ks++) {
      short8 ah = *(const short8*)(wp + (16 * t + lo) * 96 + ks * 32 + hi * 8);
      acc[t] = __builtin_amdgcn_mfma_f32_16x16x32_bf16(ah, bf[ks].s, acc[t], 0, 0, 0);
      short8 al = *(const short8*)(wp + 4608 + (16 * t + lo) * 96 + ks * 32 + hi * 8);
      acc[t] = __builtin_amdgcn_mfma_f32_16x16x32_bf16(al, bf[ks].s, acc[t], 0, 0, 0);
    }
  }
  float* ob = out + (size_t)b * 48 * HW + sp;
  #pragma unroll
  for (int t = 0; t < 3; t++)
    #pragma unroll
    for (int r = 0; r < 4; r++)
      ob[(size_t)(16 * t + 4 * hi + r) * HW] = acc[t][r];
}

extern "C" void kernel_launch(void* const* d_in, const int* in_sizes, int n_in,
                              void* d_out, int out_size, void* d_ws, size_t ws_size,
                              hipStream_t stream) {
  const float* x    = (const float*)d_in[0];
  const float* w1a  = (const float*)d_in[1];
  const float* b1a  = (const float*)d_in[2];
  const float* wdwa = (const float*)d_in[3];
  const float* bdwa = (const float*)d_in[4];
  const float* w1c  = (const float*)d_in[5];
  const float* b1c  = (const float*)d_in[6];
  const float* wdwc = (const float*)d_in[7];
  const float* bdwc = (const float*)d_in[8];
  const float* wsca = (const float*)d_in[9];
  const float* bsca = (const float*)d_in[10];
  const float* wc2a = (const float*)d_in[11];
  const float* bc2a = (const float*)d_in[12];
  const float* wc2b = (const float*)d_in[13];
  const float* bc2b = (const float*)d_in[14];
  const float* w211 = (const float*)d_in[15];
  const float* b211 = (const float*)d_in[16];
  const float* wproj= (const float*)d_in[17];
  const float* bproj= (const float*)d_in[18];
  const float* kbw  = (const float*)d_in[19];
  const float* kbb  = (const float*)d_in[20];
  const float* attg = (const float*)d_in[21];
  const float* ga1  = (const float*)d_in[22];
  float* out = (float*)d_out;

  float* ws    = (float*)d_ws;
  float* xmean = ws;                 // 96
  float* ha    = ws + 288;           // 3145728 (later: y2)
  float* hc    = ha + 3145728;       // 3145728
  float* x1g   = hc + 3145728;       // 3145728
  float* uf    = x1g + 3145728;      // 3145728
  float* att   = uf + 3145728;       // 1048576
  float* m     = att + 1048576;      // 393216 (own region)
  unsigned int* y2 = (unsigned int*)ha;           // y2 lifetime [kba, proj]
  unsigned short* kwA = (unsigned short*)(m + 393216);  // 98304 u16
  unsigned short* wp  = kwA + 98304;                    // 9216 u16

  k_combo1<<<4082, 256, 0, stream>>>(x, w1a, b1a, w1c, b1c, w211, b211,
                                     kbw, kbb, wproj, wc2a, bc2a,
                                     xmean, ha, hc, att, kwA, wp, m);
  k_combo2<<<5120, 256, 0, stream>>>(ha, hc, wdwa, bdwa, wdwc, bdwc,
                                     wsca, bsca, xmean, m, wc2b, bc2b, attg,
                                     x1g, uf, att);
  k_kba <<<dim3(256, 12), 256, 0, stream>>>(uf, x1g, att, kwA, ga1, y2);
  k_proj<<<512, 256, 0, stream>>>(y2, wp, bproj, out);
}

// Round 18
// 81.579 us; speedup vs baseline: 1.0173x; 1.0173x over previous
//
#include <hip/hip_runtime.h>
#include <math.h>

#define HW 16384
#define Wd 128

typedef __attribute__((ext_vector_type(8))) short short8;
typedef __attribute__((ext_vector_type(4))) float f32x4;

__device__ __forceinline__ unsigned cvt_pk_bf16(float a, float b) {
  unsigned r;                                   // r = bf16(a) | bf16(b)<<16
  asm("v_cvt_pk_bf16_f32 %0, %1, %2" : "=v"(r) : "v"(a), "v"(b));
  return r;
}

__device__ __forceinline__ unsigned short bf16r(float f) {
  unsigned int u = __float_as_uint(f);
  unsigned int r = (u + 0x7FFFu + ((u >> 16) & 1u)) >> 16;   // RNE
  return (unsigned short)r;
}

// ================= LAUNCH 1: mean | pw1 | prep | gate (block ranges) =========
__global__ void k_combo1(
    const float* __restrict__ x,
    const float* __restrict__ w1a, const float* __restrict__ b1a,
    const float* __restrict__ w1c, const float* __restrict__ b1c,
    const float* __restrict__ w211, const float* __restrict__ b211,
    const float* __restrict__ kbw, const float* __restrict__ kbb,
    const float* __restrict__ wproj,
    const float* __restrict__ wc2a, const float* __restrict__ bc2a,
    float* __restrict__ xmean, float* __restrict__ ha, float* __restrict__ hc,
    float* __restrict__ att, unsigned short* __restrict__ kwA,
    unsigned short* __restrict__ wp, float* __restrict__ m) {
  int blk = blockIdx.x;
  int tid = threadIdx.x;
  if (blk < 96) {
    // ---- mean ----
    int bc = blk;
    const float* p = x + (size_t)bc * HW;
    float s = 0.f;
    for (int i = tid; i < HW; i += 256) s += p[i];
    #pragma unroll
    for (int off = 32; off > 0; off >>= 1) s += __shfl_down(s, off, 64);
    __shared__ float wsum[4];
    int lane = tid & 63, wv = tid >> 6;
    if (lane == 0) wsum[wv] = s;
    __syncthreads();
    if (tid == 0)
      xmean[bc] = (wsum[0] + wsum[1] + wsum[2] + wsum[3]) * (1.f / 16384.f);
  } else if (blk < 2144) {
    // ---- pw1 (flattened (512,4)) ----
    int bid2 = blk - 96;
    int bx = bid2 & 511, quad = bid2 >> 9;
    int lane = tid & 63;
    int wv = __builtin_amdgcn_readfirstlane((int)(tid >> 6));
    int slot = __builtin_amdgcn_readfirstlane(quad * 4 + wv);
    int p = bx * 64 + lane;
    int b = p >> 14, sp = p & (HW - 1);
    const float* xb = x + (size_t)b * 48 * HW + sp;
    float xv[48];
    #pragma unroll
    for (int ci = 0; ci < 48; ci++) xv[ci] = xb[(size_t)ci * HW];
    float* hab = ha + (size_t)b * 96 * HW + sp;
    float* hcb = hc + (size_t)b * 96 * HW + sp;
    int c0 = slot * 6;
    for (int co = c0; co < c0 + 6; co++) {
      float aa = b1a[co], ac = b1c[co];
      const float* wa = w1a + co * 48;
      const float* wc = w1c + co * 48;
      #pragma unroll
      for (int ci = 0; ci < 48; ci++) { aa += wa[ci] * xv[ci]; ac += wc[ci] * xv[ci]; }
      hab[(size_t)co * HW] = aa;
      hcb[(size_t)co * HW] = ac;
    }
    float* ab = att + (size_t)b * 32 * HW + sp;
    int n0 = slot * 2;
    for (int n = n0; n < n0 + 2; n++) {
      float a2 = b211[n];
      const float* w2 = w211 + n * 48;
      #pragma unroll
      for (int ci = 0; ci < 48; ci++) a2 += w2[ci] * xv[ci];
      ab[(size_t)n * HW] = a2;
    }
  } else if (blk < 2546) {
    // ---- prep ----
    int blk2 = blk - 2144;
    if (blk2 < 384) {
      int e = blk2 * 256 + tid;                    // < 98304
      int k = e & 31, nc = (e >> 5) & 63, g = e >> 11;
      int n = nc >> 1, i = nc & 1;
      int q = k >> 3, j2 = k & 7;
      float v = 0.f;
      int jj = -1;
      if (q == 0)      { if (j2 < 5) jj = j2; }
      else if (q == 1) { if (j2 < 5) jj = 9 + j2; }
      else if (q == 2) { if (j2 < 4) jj = 5 + j2; }
      else             { if (j2 < 4) jj = 14 + j2; else if (j2 == 4) v = kbb[n * 96 + 2 * g + i]; }
      if (jj >= 0) v = kbw[n * 1728 + g * 36 + i * 18 + jj];
      kwA[e] = bf16r(v);
    } else {
      int e = (blk2 - 384) * 256 + tid;            // < 4608
      if (e < 4608) {
        float w = wproj[e];
        unsigned short h = bf16r(w);
        wp[e] = h;
        float hif = __uint_as_float((unsigned)h << 16);
        wp[4608 + e] = bf16r(w - hif);
      }
    }
  } else {
    // ---- gate ----
    int idx = (blk - 2546) * 256 + tid;            // < B*12*HW = 393216
    int sp = idx & (HW - 1);
    int bi = idx >> 14;                            // b*12+i
    int i = bi % 12, b = bi / 12;
    int r = sp >> 7, c = sp & 127;
    const float* xb = x + (size_t)b * 48 * HW;
    float t[2];
    #pragma unroll
    for (int half = 0; half < 2; half++) {
      int o = i + half * 12;
      float acc = bc2a[o];
      #pragma unroll
      for (int ic = 0; ic < 2; ic++) {
        const float* xc = xb + (size_t)(2 * o + ic) * HW;
        const float* wo = wc2a + o * 18 + ic * 9;
        #pragma unroll
        for (int t9 = 0; t9 < 9; t9++) {
          int rr = r + t9 / 3 - 1, cc = c + t9 % 3 - 1;
          float v = (((unsigned)rr < 128u) && ((unsigned)cc < 128u)) ? xc[rr * Wd + cc] : 0.f;
          acc += wo[t9] * v;
        }
      }
      t[half] = acc;
    }
    m[idx] = t[0] * t[1];
  }
}

// ================= LAUNCH 2: dw (inline sca) | att2 (block ranges) ===========
__global__ void k_combo2(
    const float* __restrict__ ha, const float* __restrict__ hc,
    const float* __restrict__ wdwa, const float* __restrict__ bdwa,
    const float* __restrict__ wdwc, const float* __restrict__ bdwc,
    const float* __restrict__ wsca, const float* __restrict__ bsca,
    const float* __restrict__ xmean,
    const float* __restrict__ m,
    const float* __restrict__ wc2b, const float* __restrict__ bc2b,
    const float* __restrict__ attg,
    float* __restrict__ x1g, float* __restrict__ uf, float* __restrict__ att) {
  int blk = blockIdx.x;
  int tid = threadIdx.x;
  if (blk < 3072) {
    // ---- dw, 4-px column strips; sca computed per block from xmean ----
    int idx = blk * 256 + tid;                     // < B*96*HW/4 = 786432
    int sp4 = idx & 4095;
    int bc = idx >> 12;                            // block-uniform
    int ch = bc % 96, bq = bc / 96;
    __shared__ float scs;
    if (tid == 0) {
      float a = bsca[ch];
      for (int ci = 0; ci < 48; ci++) a += wsca[ch * 48 + ci] * xmean[bq * 48 + ci];
      scs = a;
    }
    __syncthreads();
    int sp = sp4 * 4;
    int r = sp >> 7, c = sp & 127;                 // c in {0,4,...,124}
    const float* pa = ha + (size_t)bc * HW;
    const float* pc = hc + (size_t)bc * HW;
    bool cm = (c > 0), cp = (c < 124);
    float aa0 = bdwa[ch], aa1 = aa0, aa2 = aa0, aa3 = aa0;
    float gc0 = bdwc[ch], gc1 = gc0, gc2 = gc0, gc3 = gc0;
    #pragma unroll
    for (int ri = 0; ri < 3; ri++) {
      int rr = r + ri - 1;
      bool okr = ((unsigned)rr < 128u);
      const float* ra = pa + rr * Wd + c;
      const float* rc = pc + rr * Wd + c;
      float4 fa = okr ? *(const float4*)ra : make_float4(0.f, 0.f, 0.f, 0.f);
      float4 fc = okr ? *(const float4*)rc : make_float4(0.f, 0.f, 0.f, 0.f);
      float la = (okr && cm) ? ra[-1] : 0.f;
      float lc = (okr && cm) ? rc[-1] : 0.f;
      float ua = (okr && cp) ? ra[4] : 0.f;
      float uc = (okr && cp) ? rc[4] : 0.f;
      float wa0 = wdwa[ch * 9 + ri * 3], wa1 = wdwa[ch * 9 + ri * 3 + 1], wa2 = wdwa[ch * 9 + ri * 3 + 2];
      float wc0 = wdwc[ch * 9 + ri * 3], wc1 = wdwc[ch * 9 + ri * 3 + 1], wc2 = wdwc[ch * 9 + ri * 3 + 2];
      aa0 += wa0 * la   + wa1 * fa.x + wa2 * fa.y;
      aa1 += wa0 * fa.x + wa1 * fa.y + wa2 * fa.z;
      aa2 += wa0 * fa.y + wa1 * fa.z + wa2 * fa.w;
      aa3 += wa0 * fa.z + wa1 * fa.w + wa2 * ua;
      gc0 += wc0 * lc   + wc1 * fc.x + wc2 * fc.y;
      gc1 += wc0 * fc.x + wc1 * fc.y + wc2 * fc.z;
      gc2 += wc0 * fc.y + wc1 * fc.z + wc2 * fc.w;
      gc3 += wc0 * fc.z + wc1 * fc.w + wc2 * uc;
    }
    float sc = scs;
    const float k = 0.70710678118654752440f;
    float4 xg;
    xg.x = aa0 * 0.5f * (1.f + erff(aa0 * k)) * sc;
    xg.y = aa1 * 0.5f * (1.f + erff(aa1 * k)) * sc;
    xg.z = aa2 * 0.5f * (1.f + erff(aa2 * k)) * sc;
    xg.w = aa3 * 0.5f * (1.f + erff(aa3 * k)) * sc;
    *(float4*)(x1g + (size_t)bc * HW + sp) = xg;
    *(float4*)(uf + (size_t)bc * HW + sp) = make_float4(gc0, gc1, gc2, gc3);
  } else {
    // ---- att2 (flattened (512,4)): att += 1x1(m)*gamma, in place ----
    int bid2 = blk - 3072;
    int bx = bid2 & 511, quad = bid2 >> 9;
    int lane = tid & 63;
    int wv = __builtin_amdgcn_readfirstlane((int)(tid >> 6));
    int slot = __builtin_amdgcn_readfirstlane(quad * 4 + wv);
    int p = bx * 64 + lane;
    int b = p >> 14, sp = p & (HW - 1);
    float mv[12];
    const float* mb = m + (size_t)b * 12 * HW + sp;
    #pragma unroll
    for (int i = 0; i < 12; i++) mv[i] = mb[(size_t)i * HW];
    float* ab = att + (size_t)b * 32 * HW + sp;
    int n0 = slot * 2;
    for (int n = n0; n < n0 + 2; n++) {
      float a1 = bc2b[n];
      #pragma unroll
      for (int i = 0; i < 12; i++) a1 += wc2b[n * 12 + i] * mv[i];
      float* ap = ab + (size_t)n * HW;
      *ap = a1 * attg[n] + *ap;
    }
  }
}

// ---------------- K6: fused kba via MFMA (r16 winner: 4 groups/block) ----------
// grid (512,12) x 256. Wave wv owns px [wv*16,+16); block covers 4 groups gq*4..+3.
// kwA staged in LDS (16 KB); all loop-body global reads (20 taps, 8 x1g, 8 att)
// prefetched in the preamble -> loop body is pure LDS+MFMA+VALU + y2 stores.
__global__ __launch_bounds__(256) void k_kba(
    const float* __restrict__ uf, const float* __restrict__ x1g,
    const float* __restrict__ att, const unsigned short* __restrict__ kwA,
    const float* __restrict__ ga1, unsigned int* __restrict__ y2) {
  __shared__ __align__(16) short kwS[4 * 2048];    // 16 KB
  int tid = threadIdx.x;
  int lane = tid & 63;
  int wv = tid >> 6;
  int lo = lane & 15, hi = lane >> 4;
  int bid = blockIdx.x;                            // 0..511
  int b = bid >> 8;
  int sp = ((bid & 255) << 6) + wv * 16 + lo;      // this lane's pixel
  int r = sp >> 7, c = sp & 127;
  int g0 = blockIdx.y * 4;

  {
    const short8* src = (const short8*)(kwA + g0 * 2048);
    short8* dst = (short8*)kwS;
    #pragma unroll
    for (int i = 0; i < 4; i++) dst[tid + 256 * i] = src[tid + 256 * i];
  }

  const float* ufb  = uf  + (size_t)b * 96 * HW;
  const float* x1gb = x1g + (size_t)b * 96 * HW;
  const float* attb = att + (size_t)b * 32 * HW;
  unsigned int* y2b = y2 + (size_t)b * 48 * HW;

  float attv[8];
  #pragma unroll
  for (int mt = 0; mt < 4; mt++)
    #pragma unroll
    for (int q = 0; q < 2; q++)
      attv[mt * 2 + q] = attb[(size_t)(8 * mt + 2 * hi + q) * HW + sp];

  const float* pj[5];
  bool ok[5];
  float dv[5];
  #pragma unroll
  for (int j2 = 0; j2 < 5; j2++) {
    int jj = (hi == 0) ? j2 : (hi == 1) ? 9 + j2 : (hi == 2) ? 5 + j2 : 14 + j2;
    bool real = (hi < 2) || (j2 < 4);
    if (real) {
      int ch = jj / 9, tap = jj % 9;
      int rr = r + tap / 3 - 1, cc = c + tap % 3 - 1;
      bool inb = ((unsigned)rr < 128u) && ((unsigned)cc < 128u);
      ok[j2] = inb;
      dv[j2] = 0.f;
      pj[j2] = ufb + (size_t)(2 * g0 + ch) * HW + (inb ? rr * Wd + cc : 0);
    } else {
      ok[j2] = false;
      dv[j2] = (hi == 3) ? 1.f : 0.f;              // bias slot (q3, j2==4)
      pj[j2] = ufb;
    }
  }

  float vT[4][5];
  #pragma unroll
  for (int gi = 0; gi < 4; gi++)
    #pragma unroll
    for (int j2 = 0; j2 < 5; j2++)
      vT[gi][j2] = ok[j2] ? pj[j2][(size_t)(2 * gi) * HW] : dv[j2];
  float x1v[8];
  #pragma unroll
  for (int k = 0; k < 8; k++)
    x1v[k] = x1gb[(size_t)(2 * g0 + k) * HW + sp];

  __syncthreads();

  #pragma unroll
  for (int gp = 0; gp < 2; gp++) {
    int g = g0 + 2 * gp;
    float* va = vT[2 * gp];
    float* vb = vT[2 * gp + 1];
    const short* kgA = kwS + (2 * gp) * 2048;
    const short* kgB = kgA + 2048;
    short8 afrA[4], afrB[4];
    #pragma unroll
    for (int mt = 0; mt < 4; mt++) {
      afrA[mt] = *(const short8*)(kgA + (16 * mt + lo) * 32 + hi * 8);
      afrB[mt] = *(const short8*)(kgB + (16 * mt + lo) * 32 + hi * 8);
    }
    union { unsigned u[4]; short8 s; } bfA, bfB;
    bfA.u[0] = cvt_pk_bf16(va[0], va[1]);
    bfA.u[1] = cvt_pk_bf16(va[2], va[3]);
    bfA.u[2] = cvt_pk_bf16(va[4], 0.f);
    bfA.u[3] = 0u;
    bfB.u[0] = cvt_pk_bf16(vb[0], vb[1]);
    bfB.u[1] = cvt_pk_bf16(vb[2], vb[3]);
    bfB.u[2] = cvt_pk_bf16(vb[4], 0.f);
    bfB.u[3] = 0u;
    f32x4 accA[4], accB[4];
    f32x4 zero = {0.f, 0.f, 0.f, 0.f};
    #pragma unroll
    for (int mt = 0; mt < 4; mt++)
      accA[mt] = __builtin_amdgcn_mfma_f32_16x16x32_bf16(afrA[mt], bfA.s, zero, 0, 0, 0);
    #pragma unroll
    for (int mt = 0; mt < 4; mt++)
      accB[mt] = __builtin_amdgcn_mfma_f32_16x16x32_bf16(afrB[mt], bfB.s, zero, 0, 0, 0);
    float sA0 = 0.f, sA1 = 0.f, sB0 = 0.f, sB1 = 0.f;
    #pragma unroll
    for (int mt = 0; mt < 4; mt++) {
      sA0 += attv[mt * 2 + 0] * accA[mt][0] + attv[mt * 2 + 1] * accA[mt][2];
      sA1 += attv[mt * 2 + 0] * accA[mt][1] + attv[mt * 2 + 1] * accA[mt][3];
    }
    sA0 += __shfl_xor(sA0, 16); sA0 += __shfl_xor(sA0, 32);
    sA1 += __shfl_xor(sA1, 16); sA1 += __shfl_xor(sA1, 32);
    float cenA = __shfl_xor(va[4], 16);
    #pragma unroll
    for (int mt = 0; mt < 4; mt++) {
      sB0 += attv[mt * 2 + 0] * accB[mt][0] + attv[mt * 2 + 1] * accB[mt][2];
      sB1 += attv[mt * 2 + 0] * accB[mt][1] + attv[mt * 2 + 1] * accB[mt][3];
    }
    sB0 += __shfl_xor(sB0, 16); sB0 += __shfl_xor(sB0, 32);
    sB1 += __shfl_xor(sB1, 16); sB1 += __shfl_xor(sB1, 32);
    float cenB = __shfl_xor(vb[4], 16);
    if (hi == 0) {
      int c0 = 2 * g;
      float xa0 = sA0 * ga1[c0]     + va[4];
      float xa1 = sA1 * ga1[c0 + 1] + cenA;
      float ya0 = x1v[4 * gp]     * xa0;
      float ya1 = x1v[4 * gp + 1] * xa1;
      y2b[(size_t)g * HW + sp] = cvt_pk_bf16(ya0, ya1);
      float xb0 = sB0 * ga1[c0 + 2] + vb[4];
      float xb1 = sB1 * ga1[c0 + 3] + cenB;
      float yb0 = x1v[4 * gp + 2] * xb0;
      float yb1 = x1v[4 * gp + 3] * xb1;
      y2b[(size_t)(g + 1) * HW + sp] = cvt_pk_bf16(yb0, yb1);
    }
  }
}

// ---------------- K7: project_out 96->48 via MFMA (W = bf16 hi + bf16 lo) -------
__global__ void k_proj(const unsigned int* __restrict__ y2, const unsigned short* __restrict__ wp,
                       const float* __restrict__ bproj, float* __restrict__ out) {
  int tid = threadIdx.x;
  int lane = tid & 63;
  int wv = tid >> 6;
  int lo = lane & 15, hi = lane >> 4;
  int p0 = blockIdx.x * 64 + wv * 16;
  int b = p0 >> 14;
  int sp = (p0 & (HW - 1)) + lo;
  const unsigned int* yb = y2 + (size_t)b * 48 * HW + sp;
  union { unsigned u[4]; short8 s; } bf[3];
  #pragma unroll
  for (int ks = 0; ks < 3; ks++)
    #pragma unroll
    for (int q = 0; q < 4; q++)
      bf[ks].u[q] = yb[(size_t)(ks * 16 + hi * 4 + q) * HW];
  f32x4 acc[3];
  #pragma unroll
  for (int t = 0; t < 3; t++)
    #pragma unroll
    for (int r = 0; r < 4; r++)
      acc[t][r] = bproj[16 * t + 4 * hi + r];
  #pragma unroll
  for (int t = 0; t < 3; t++) {
    #pragma unroll
    for (int ks = 0; ks < 3; ks++) {
      short8 ah = *(const short8*)(wp + (16 * t + lo) * 96 + ks * 32 + hi * 8);
      acc[t] = __builtin_amdgcn_mfma_f32_16x16x32_bf16(ah, bf[ks].s, acc[t], 0, 0, 0);
      short8 al = *(const short8*)(wp + 4608 + (16 * t + lo) * 96 + ks * 32 + hi * 8);
      acc[t] = __builtin_amdgcn_mfma_f32_16x16x32_bf16(al, bf[ks].s, acc[t], 0, 0, 0);
    }
  }
  float* ob = out + (size_t)b * 48 * HW + sp;
  #pragma unroll
  for (int t = 0; t < 3; t++)
    #pragma unroll
    for (int r = 0; r < 4; r++)
      ob[(size_t)(16 * t + 4 * hi + r) * HW] = acc[t][r];
}

extern "C" void kernel_launch(void* const* d_in, const int* in_sizes, int n_in,
                              void* d_out, int out_size, void* d_ws, size_t ws_size,
                              hipStream_t stream) {
  const float* x    = (const float*)d_in[0];
  const float* w1a  = (const float*)d_in[1];
  const float* b1a  = (const float*)d_in[2];
  const float* wdwa = (const float*)d_in[3];
  const float* bdwa = (const float*)d_in[4];
  const float* w1c  = (const float*)d_in[5];
  const float* b1c  = (const float*)d_in[6];
  const float* wdwc = (const float*)d_in[7];
  const float* bdwc = (const float*)d_in[8];
  const float* wsca = (const float*)d_in[9];
  const float* bsca = (const float*)d_in[10];
  const float* wc2a = (const float*)d_in[11];
  const float* bc2a = (const float*)d_in[12];
  const float* wc2b = (const float*)d_in[13];
  const float* bc2b = (const float*)d_in[14];
  const float* w211 = (const float*)d_in[15];
  const float* b211 = (const float*)d_in[16];
  const float* wproj= (const float*)d_in[17];
  const float* bproj= (const float*)d_in[18];
  const float* kbw  = (const float*)d_in[19];
  const float* kbb  = (const float*)d_in[20];
  const float* attg = (const float*)d_in[21];
  const float* ga1  = (const float*)d_in[22];
  float* out = (float*)d_out;

  float* ws    = (float*)d_ws;
  float* xmean = ws;                 // 96
  float* ha    = ws + 288;           // 3145728 (later: y2)
  float* hc    = ha + 3145728;       // 3145728
  float* x1g   = hc + 3145728;       // 3145728
  float* uf    = x1g + 3145728;      // 3145728
  float* att   = uf + 3145728;       // 1048576
  float* m     = att + 1048576;      // 393216 (own region)
  unsigned int* y2 = (unsigned int*)ha;           // y2 lifetime [kba, proj]
  unsigned short* kwA = (unsigned short*)(m + 393216);  // 98304 u16
  unsigned short* wp  = kwA + 98304;                    // 9216 u16

  k_combo1<<<4082, 256, 0, stream>>>(x, w1a, b1a, w1c, b1c, w211, b211,
                                     kbw, kbb, wproj, wc2a, bc2a,
                                     xmean, ha, hc, att, kwA, wp, m);
  k_combo2<<<5120, 256, 0, stream>>>(ha, hc, wdwa, bdwa, wdwc, bdwc,
                                     wsca, bsca, xmean, m, wc2b, bc2b, attg,
                                     x1g, uf, att);
  k_kba <<<dim3(512, 12), 256, 0, stream>>>(uf, x1g, att, kwA, ga1, y2);
  k_proj<<<512, 256, 0, stream>>>(y2, wp, bproj, out);
}